// Round 1
// baseline (1297.743 us; speedup 1.0000x reference)
//
#include <hip/hip_runtime.h>
#include <float.h>

// ScalarDotAttention: B=16, L=2048, D=128, fp32.
// Multiplicative causal mask: k>=q => score *= -1e9  (softmax is ~one-hot at
// argmin of raw score over masked region for almost all rows).
// Flash-style online softmax, fp32 vector FMA for QK^T (no fp32 MFMA on CDNA4,
// and bf16 would flip the argmin). PV skipped per-tile via ballot mask of
// non-underflowed exp() values.

constexpr int Bc = 16;
constexpr int Lc = 2048;
constexpr int Dc = 128;
constexpr float INV_DENOM = 0.022097086912079608f;  // 1/sqrt(2048)

__global__ __launch_bounds__(256, 2)
void sda_fwd(const float* __restrict__ Qg, const float* __restrict__ Kg,
             const float* __restrict__ Vg, const int* __restrict__ maskp,
             float* __restrict__ Og) {
  // Q tile 64x128 (32 KB), K tile 32x128 (16 KB), per-wave P 16x32 (8 KB total)
  __shared__ float Qs[64 * 128];
  __shared__ float Ks[32 * 128];
  __shared__ float Ps[4][16 * 32];

  const int t = threadIdx.x;
  const int w = t >> 6;        // wave 0..3
  const int l = t & 63;
  const int qrow = l >> 2;     // 0..15 row within wave
  const int c = l & 3;         // k-interleave / d-quarter lane group

  const int b = blockIdx.x >> 5;
  const int q0 = (blockIdx.x & 31) << 6;
  const int qloc = (w << 4) + qrow;    // 0..63
  const int qglob = q0 + qloc;

  const int maskf = maskp[0];

  const float* Qbase = Qg + ((size_t)b * Lc + q0) * Dc;
  const float* Kb = Kg + (size_t)b * Lc * Dc;
  const float* Vb = Vg + (size_t)b * Lc * Dc;

  // ---- stage Q tile, XOR-swizzled 16B chunks: chunk m of row r -> m^(r&7) ----
  #pragma unroll
  for (int i = 0; i < 8; ++i) {
    int n = t + (i << 8);            // chunk 0..2047
    int r = n >> 5, m = n & 31;
    float4 v = *(const float4*)(Qbase + ((size_t)n << 2));
    *(float4*)(&Qs[r * 128 + ((m ^ (r & 7)) << 2)]) = v;
  }

  float4 O[8];
  #pragma unroll
  for (int u = 0; u < 8; ++u) O[u] = make_float4(0.f, 0.f, 0.f, 0.f);
  float mrun = -FLT_MAX;
  float lrun = 0.f;

  const int xq = qloc & 7;
  const float* Qrow = &Qs[qloc * 128];

  for (int kt = 0; kt < 64; ++kt) {
    __syncthreads();   // prev tile's K reads done (and Q staged, at kt=0)
    const float* Ksrc = Kb + (size_t)(kt << 5) * Dc;
    #pragma unroll
    for (int i = 0; i < 4; ++i) {
      int n = t + (i << 8);          // chunk 0..1023
      int r = n >> 5, m = n & 31;
      float4 v = *(const float4*)(Ksrc + ((size_t)n << 2));
      *(float4*)(&Ks[r * 128 + ((m ^ (r & 7)) << 2)]) = v;
    }
    __syncthreads();

    // ---- S = Q . K^T : lane computes 8 dots (row qloc x k = c+4ki) ----
    float S[8];
    #pragma unroll
    for (int ki = 0; ki < 8; ++ki) S[ki] = 0.f;

    #pragma unroll
    for (int j = 0; j < 32; ++j) {
      float4 qv = *(const float4*)(Qrow + ((j ^ xq) << 2));
      #pragma unroll
      for (int ki = 0; ki < 8; ++ki) {
        const int kl = c + (ki << 2);
        float4 kv = *(const float4*)(&Ks[kl * 128 + ((j ^ (kl & 7)) << 2)]);
        S[ki] = fmaf(qv.x, kv.x, S[ki]);
        S[ki] = fmaf(qv.y, kv.y, S[ki]);
        S[ki] = fmaf(qv.z, kv.z, S[ki]);
        S[ki] = fmaf(qv.w, kv.w, S[ki]);
      }
    }

    // ---- multiplicative mask + online softmax ----
    float xv[8];
    float tmax = -FLT_MAX;
    #pragma unroll
    for (int ki = 0; ki < 8; ++ki) {
      int kg = (kt << 5) + c + (ki << 2);
      float mult = (maskf && kg >= qglob) ? -1.0e9f : 1.0f;
      float x = S[ki] * mult * INV_DENOM;
      xv[ki] = x;
      tmax = fmaxf(tmax, x);
    }
    tmax = fmaxf(tmax, __shfl_xor(tmax, 1));
    tmax = fmaxf(tmax, __shfl_xor(tmax, 2));

    float mnew = fmaxf(mrun, tmax);
    float alpha = __expf(mrun - mnew);

    float pv[8];
    float tsum = 0.f;
    #pragma unroll
    for (int ki = 0; ki < 8; ++ki) {
      float p = __expf(xv[ki] - mnew);
      pv[ki] = p;
      tsum += p;
    }
    tsum += __shfl_xor(tsum, 1);
    tsum += __shfl_xor(tsum, 2);

    lrun = lrun * alpha + tsum;
    mrun = mnew;

    // ---- per-wave live-k bitmask: bit (c+4ki) = any row has p>0 ----
    unsigned long long kmask = 0ull;
    #pragma unroll
    for (int ki = 0; ki < 8; ++ki) {
      unsigned long long bal = __ballot(pv[ki] > 0.0f);
      bal |= bal >> 32; bal |= bal >> 16; bal |= bal >> 8; bal |= bal >> 4;
      kmask |= (bal & 0xFull) << (ki << 2);
    }
    const bool needresc = __any(alpha < 1.0f);

    if (needresc) {
      #pragma unroll
      for (int u = 0; u < 8; ++u) {
        O[u].x *= alpha; O[u].y *= alpha; O[u].z *= alpha; O[u].w *= alpha;
      }
    }
    if (kmask) {
      // route P through swizzled per-wave LDS (write pos = k ^ ((qrow&7)<<2))
      #pragma unroll
      for (int ki = 0; ki < 8; ++ki) {
        int kl = c + (ki << 2);
        Ps[w][(qrow << 5) + (kl ^ ((qrow & 7) << 2))] = pv[ki];
      }
      unsigned long long mrem = kmask;   // wave-uniform scalar loop
      while (mrem) {
        int k = __ffsll((unsigned long long)mrem) - 1;
        mrem &= mrem - 1;
        float p = Ps[w][(qrow << 5) + (k ^ ((qrow & 7) << 2))];
        const float4* Vr = (const float4*)(Vb + (size_t)((kt << 5) + k) * Dc);
        #pragma unroll
        for (int u = 0; u < 8; ++u) {
          float4 vv = Vr[c + (u << 2)];   // lane owns d = (c+4u)*4 .. +3
          O[u].x = fmaf(p, vv.x, O[u].x);
          O[u].y = fmaf(p, vv.y, O[u].y);
          O[u].z = fmaf(p, vv.z, O[u].z);
          O[u].w = fmaf(p, vv.w, O[u].w);
        }
      }
    }
  }

  const float invl = 1.0f / lrun;
  float4* Orow = (float4*)(Og + ((size_t)b * Lc + qglob) * Dc);
  #pragma unroll
  for (int u = 0; u < 8; ++u) {
    float4 o = O[u];
    o.x *= invl; o.y *= invl; o.z *= invl; o.w *= invl;
    Orow[c + (u << 2)] = o;
  }
}

extern "C" void kernel_launch(void* const* d_in, const int* in_sizes, int n_in,
                              void* d_out, int out_size, void* d_ws, size_t ws_size,
                              hipStream_t stream) {
  const float* Q = (const float*)d_in[0];
  const float* K = (const float*)d_in[1];
  const float* V = (const float*)d_in[2];
  const int* M = (const int*)d_in[3];
  float* O = (float*)d_out;
  dim3 grid(Bc * (Lc / 64)), block(256);
  hipLaunchKernelGGL(sda_fwd, grid, block, 0, stream, Q, K, V, M, O);
}

// Round 2
// 924.138 us; speedup vs baseline: 1.4043x; 1.4043x over previous
//
#include <hip/hip_runtime.h>
#include <float.h>

// ScalarDotAttention B=16, L=2048, D=128 fp32.
// Multiplicative causal mask (k>=q: score *= -1e9) => softmax is ~one-hot at
// argmin of raw masked score for almost all rows. fp32 vector FMA for QK^T
// (no fp32 MFMA; bf16 would flip the argmin). Register-tiled 4qx8k GEMM,
// global_load_lds double-buffered K staging with counted vmcnt, dead-tile
// skip for softmax/PV.

constexpr int Bc = 16;
constexpr int Lc = 2048;
constexpr int Dc = 128;
constexpr float INV_DENOM = 0.022097086912079608f;   // 1/sqrt(2048)
constexpr float MNEG = -1.0e9f * INV_DENOM;          // masked multiplier
constexpr float PCUT = 1e-30f;

typedef __attribute__((address_space(1))) const void* as1cv;
typedef __attribute__((address_space(3))) void* as3v;

__device__ __forceinline__ void gload16(const void* g, void* l) {
  __builtin_amdgcn_global_load_lds((as1cv)g, (as3v)l, 16, 0, 0);
}

__global__ __launch_bounds__(256, 2)
void sda_fwd(const float* __restrict__ Qg, const float* __restrict__ Kg,
             const float* __restrict__ Vg, const int* __restrict__ maskp,
             float* __restrict__ Og) {
  __shared__ float Qs[64 * 128];        // 32 KB, linear
  __shared__ float Ks[2][128 * 32];     // 2 x 16 KB, chunk-swizzled rows

  const int t = threadIdx.x;
  const int w = t >> 6, l = t & 63;
  const int qg = l >> 4, kl = l & 15;   // lane owns 4 q-rows (qg), 8 k-cols (kl+16j)
  const int b = blockIdx.x >> 5;
  const int q0 = (blockIdx.x & 31) << 6;
  const int maskf = maskp[0];

  const float* Qbase = Qg + ((size_t)b * Lc + q0) * Dc;
  const float* Kb = Kg + (size_t)b * Lc * Dc;
  const float* Vb = Vg + (size_t)b * Lc * Dc;

  // ---- stage Q tile 64x128 (linear; 8 gload16 per wave) ----
  #pragma unroll
  for (int u = 0; u < 8; ++u) {
    int n = (w << 9) + (u << 6) + l;            // float4 index 0..2047
    gload16(Qbase + ((size_t)n << 2), &Qs[n << 2]);
  }
  // ---- stage K chunk 0 (kt=0, dc=0) pre-swizzled source ----
  {
    const float* src = Kb;
    #pragma unroll
    for (int u = 0; u < 4; ++u) {
      int n = (w << 8) + (u << 6) + l;          // float4 index 0..1023
      int kr = n >> 3, s = n & 7, m = s ^ (kr & 7);
      gload16(src + kr * 128 + (m << 2), &Ks[0][n << 2]);
    }
  }

  float acc[4][8];
  #pragma unroll
  for (int i = 0; i < 4; ++i)
    #pragma unroll
    for (int j = 0; j < 8; ++j) acc[i][j] = 0.f;

  float4 Ob[4][2];
  #pragma unroll
  for (int i = 0; i < 4; ++i) {
    Ob[i][0] = make_float4(0.f, 0.f, 0.f, 0.f);
    Ob[i][1] = make_float4(0.f, 0.f, 0.f, 0.f);
  }
  float m_[4], l_[4];
  #pragma unroll
  for (int i = 0; i < 4; ++i) { m_[i] = -FLT_MAX; l_[i] = 0.f; }

  const int qrb = q0 + (w << 4) + (qg << 2);          // first of lane's 4 q rows
  const float* qb = &Qs[((w << 4) + (qg << 2)) * 128];
  const int xk16 = (kl & 7) << 4;                     // byte xor for K swizzle

  for (int c = 0; c < 64; ++c) {                      // 16 k-tiles x 4 d-chunks
    // ---- prefetch next chunk into other buffer, then counted wait ----
    if (c < 63) {
      const int c1 = c + 1;
      const float* src = Kb + (size_t)((c1 >> 2) << 7) * 128 + ((c1 & 3) << 5);
      float* dst = &Ks[c1 & 1][0];
      #pragma unroll
      for (int u = 0; u < 4; ++u) {
        int n = (w << 8) + (u << 6) + l;
        int kr = n >> 3, s = n & 7, m = s ^ (kr & 7);
        gload16(src + kr * 128 + (m << 2), dst + (n << 2));
      }
      asm volatile("s_waitcnt vmcnt(4)" ::: "memory");
    } else {
      asm volatile("s_waitcnt vmcnt(0)" ::: "memory");
    }
    asm volatile("s_barrier" ::: "memory");

    // ---- compute: acc += Q[:, dc*32..+32) . K^T ----
    {
      const float* qc = qb + ((c & 3) << 5);
      const char* kb2 = (const char*)(&Ks[c & 1][0]) + (kl << 7);  // kl*128B
      #pragma unroll
      for (int jj = 0; jj < 8; ++jj) {
        float4 qv[4];
        #pragma unroll
        for (int i = 0; i < 4; ++i)
          qv[i] = *(const float4*)(qc + (i << 7) + (jj << 2));
        const char* kp = kb2 + (xk16 ^ (jj << 4));
        #pragma unroll
        for (int j = 0; j < 8; ++j) {
          float4 kv = *(const float4*)(kp + (j << 11));  // +16 rows = 2048B
          #pragma unroll
          for (int i = 0; i < 4; ++i) {
            acc[i][j] = fmaf(qv[i].x, kv.x, acc[i][j]);
            acc[i][j] = fmaf(qv[i].y, kv.y, acc[i][j]);
            acc[i][j] = fmaf(qv[i].z, kv.z, acc[i][j]);
            acc[i][j] = fmaf(qv[i].w, kv.w, acc[i][j]);
          }
        }
      }
    }

    // ---- end of k-tile: mask, online softmax, sparse PV ----
    if ((c & 3) == 3) {
      const int kt0 = (c >> 2) << 7;   // first col of this 128-wide tile
      #pragma unroll
      for (int i = 0; i < 4; ++i) {
        #pragma unroll
        for (int j = 0; j < 8; ++j) {
          int kg = kt0 + kl + (j << 4);
          float mult = (maskf && kg >= qrb + i) ? MNEG : INV_DENOM;
          acc[i][j] *= mult;
        }
      }
      float rmax[4];
      #pragma unroll
      for (int i = 0; i < 4; ++i) {
        float v = acc[i][0];
        #pragma unroll
        for (int j = 1; j < 8; ++j) v = fmaxf(v, acc[i][j]);
        v = fmaxf(v, __shfl_xor(v, 1));
        v = fmaxf(v, __shfl_xor(v, 2));
        v = fmaxf(v, __shfl_xor(v, 4));
        v = fmaxf(v, __shfl_xor(v, 8));
        rmax[i] = v;
      }
      bool live = (rmax[0] > m_[0] - 80.f) || (rmax[1] > m_[1] - 80.f) ||
                  (rmax[2] > m_[2] - 80.f) || (rmax[3] > m_[3] - 80.f);
      if (__any((int)live)) {
        #pragma unroll
        for (int i = 0; i < 4; ++i) {
          float mnew = fmaxf(m_[i], rmax[i]);
          float alpha = __expf(m_[i] - mnew);
          m_[i] = mnew;
          float ts = 0.f;
          #pragma unroll
          for (int j = 0; j < 8; ++j) {
            float p = __expf(acc[i][j] - mnew);
            acc[i][j] = p;
            ts += p;
          }
          ts += __shfl_xor(ts, 1);
          ts += __shfl_xor(ts, 2);
          ts += __shfl_xor(ts, 4);
          ts += __shfl_xor(ts, 8);
          l_[i] = l_[i] * alpha + ts;
          Ob[i][0].x *= alpha; Ob[i][0].y *= alpha; Ob[i][0].z *= alpha; Ob[i][0].w *= alpha;
          Ob[i][1].x *= alpha; Ob[i][1].y *= alpha; Ob[i][1].z *= alpha; Ob[i][1].w *= alpha;
        }
        #pragma unroll
        for (int j = 0; j < 8; ++j) {
          bool pr = (acc[0][j] > PCUT) || (acc[1][j] > PCUT) ||
                    (acc[2][j] > PCUT) || (acc[3][j] > PCUT);
          unsigned long long bal = __ballot((int)pr);
          bal |= bal >> 32; bal |= bal >> 16;
          unsigned mm = (unsigned)bal & 0xFFFFu;
          while (mm) {
            int bit = __ffs(mm) - 1;
            mm &= mm - 1;
            int col = kt0 + (j << 4) + bit;
            float pp[4];
            pp[0] = __shfl(acc[0][j], (qg << 4) + bit);
            pp[1] = __shfl(acc[1][j], (qg << 4) + bit);
            pp[2] = __shfl(acc[2][j], (qg << 4) + bit);
            pp[3] = __shfl(acc[3][j], (qg << 4) + bit);
            const float4* Vr = (const float4*)(Vb + (size_t)col * Dc) + (kl << 1);
            float4 v0 = Vr[0], v1 = Vr[1];
            #pragma unroll
            for (int i = 0; i < 4; ++i) {
              Ob[i][0].x = fmaf(pp[i], v0.x, Ob[i][0].x);
              Ob[i][0].y = fmaf(pp[i], v0.y, Ob[i][0].y);
              Ob[i][0].z = fmaf(pp[i], v0.z, Ob[i][0].z);
              Ob[i][0].w = fmaf(pp[i], v0.w, Ob[i][0].w);
              Ob[i][1].x = fmaf(pp[i], v1.x, Ob[i][1].x);
              Ob[i][1].y = fmaf(pp[i], v1.y, Ob[i][1].y);
              Ob[i][1].z = fmaf(pp[i], v1.z, Ob[i][1].z);
              Ob[i][1].w = fmaf(pp[i], v1.w, Ob[i][1].w);
            }
          }
        }
      }
      #pragma unroll
      for (int i = 0; i < 4; ++i)
        #pragma unroll
        for (int j = 0; j < 8; ++j) acc[i][j] = 0.f;
    }
    if (c < 63) asm volatile("s_barrier" ::: "memory");
  }

  // ---- epilogue: normalize, store ----
  #pragma unroll
  for (int i = 0; i < 4; ++i) {
    float inv = 1.0f / l_[i];
    float4 o0 = Ob[i][0], o1 = Ob[i][1];
    o0.x *= inv; o0.y *= inv; o0.z *= inv; o0.w *= inv;
    o1.x *= inv; o1.y *= inv; o1.z *= inv; o1.w *= inv;
    float4* Or = (float4*)(Og + ((size_t)b * Lc + qrb + i) * Dc) + (kl << 1);
    Or[0] = o0;
    Or[1] = o1;
  }
}

extern "C" void kernel_launch(void* const* d_in, const int* in_sizes, int n_in,
                              void* d_out, int out_size, void* d_ws, size_t ws_size,
                              hipStream_t stream) {
  (void)in_sizes; (void)n_in; (void)d_ws; (void)ws_size; (void)out_size;
  const float* Q = (const float*)d_in[0];
  const float* K = (const float*)d_in[1];
  const float* V = (const float*)d_in[2];
  const int* M = (const int*)d_in[3];
  float* O = (float*)d_out;
  dim3 grid(Bc * (Lc / 64)), block(256);
  hipLaunchKernelGGL(sda_fwd, grid, block, 0, stream, Q, K, V, M, O);
}

// Round 4
// 397.978 us; speedup vs baseline: 3.2608x; 2.3221x over previous
//
#include <hip/hip_runtime.h>
#include <float.h>

// ScalarDotAttention B=16, L=2048, D=128 fp32, multiplicative causal mask
// (k>=q: score *= -1e9). For mask=1 the softmax is exactly one-hot at
// argmin_{k>=q} s (2-term blend if gap < ~4e-6), EXCEPT rows whose masked
// min is ~>=0 (prob 2^-(2048-q)) which need the dense prefix softmax.
// Pass A: upper-triangle-only fp32 QK^T tracking (min1,idx1,min2,idx2) per
// row -- no exp, no PV. Epilogue: 2-term V gather. Pass B (rare, barrier-
// free): exact dense softmax per flagged row, one wave per row.

constexpr int Bc = 16;
constexpr int Lc = 2048;
constexpr int Dc = 128;
constexpr float INV_DENOM = 0.022097086912079608f;   // 1/sqrt(2048)
constexpr float MNEG = -1.0e9f * INV_DENOM;

typedef __attribute__((address_space(1))) const void* as1cv;
typedef __attribute__((address_space(3))) void* as3v;

__device__ __forceinline__ void gload16(const void* g, void* l) {
  __builtin_amdgcn_global_load_lds((as1cv)g, (as3v)l, 16, 0, 0);
}

__global__ __launch_bounds__(256, 2)
void sda_fwd(const float* __restrict__ Qg, const float* __restrict__ Kg,
             const float* __restrict__ Vg, const int* __restrict__ maskp,
             float* __restrict__ Og) {
  __shared__ float Qs[64 * 128];        // 32 KB, row-swizzled chunks
  __shared__ float Ks[2][128 * 32];     // 2 x 16 KB dbuf (pass-B scratch later)

  const int t = threadIdx.x;
  const int w = t >> 6, l = t & 63;
  const int qg = l >> 4, kl = l & 15;

  // complementary work pairing: (bid, bid+256) -> q-tiles (2p, 31-2p)
  const int bid = blockIdx.x;
  int b, qt;
  if (bid < 256) { b = bid & 15; qt = (bid >> 4) << 1; }
  else { int j = bid - 256; b = j & 15; qt = 31 - ((j >> 4) << 1); }
  const int q0 = qt << 6;
  const int maskf = maskp[0];

  const float* Qbase = Qg + ((size_t)b * Lc + q0) * Dc;
  const float* Kb = Kg + (size_t)b * Lc * Dc;
  const float* Vb = Vg + (size_t)b * Lc * Dc;

  // ---- stage Q tile 64x128, chunk-swizzled: phys m holds logical m^((r>>1)&7) ----
  #pragma unroll
  for (int u = 0; u < 8; ++u) {
    int n = (w << 9) + (u << 6) + l;     // float4 chunk 0..2047
    int r = n >> 5, m = n & 31;
    int ms = m ^ ((r >> 1) & 7);
    gload16(Qbase + (((size_t)r << 5 | ms) << 2), &Qs[n << 2]);
  }

  const int t0 = maskf ? (q0 >> 7) : 16;     // first k-tile (diagonal); mask=0 -> skip
  const int c0 = t0 << 2;

  if (c0 < 64) {   // stage K chunk c0
    const float* src = Kb + (size_t)((c0 >> 2) << 7) * Dc + ((c0 & 3) << 5);
    #pragma unroll
    for (int u = 0; u < 4; ++u) {
      int n = (w << 8) + (u << 6) + l;
      int kr = n >> 3, s2 = n & 7, m = s2 ^ (kr & 7);
      gload16(src + kr * 128 + (m << 2), &Ks[c0 & 1][n << 2]);
    }
  }

  float acc[4][8];
  #pragma unroll
  for (int i = 0; i < 4; ++i)
    #pragma unroll
    for (int j = 0; j < 8; ++j) acc[i][j] = 0.f;

  float rv1[4], rv2[4];
  int ri1[4], ri2[4];
  #pragma unroll
  for (int i = 0; i < 4; ++i) { rv1[i] = FLT_MAX; rv2[i] = FLT_MAX; ri1[i] = 0; ri2[i] = 0; }

  const int qrb = q0 + (w << 4) + (qg << 2);
  const char* qb = (const char*)&Qs[((w << 4) + (qg << 2)) * 128];
  const int xk16 = (kl & 7) << 4;
  const int s01 = (qg << 1) & 7;           // row swizzle for i=0,1
  const int s23 = ((qg << 1) + 1) & 7;     // for i=2,3

  for (int c = c0; c < 64; ++c) {          // (k-tile, 32-d-chunk) iterations
    if (c < 63) {
      const int c1 = c + 1;
      const float* src = Kb + (size_t)((c1 >> 2) << 7) * Dc + ((c1 & 3) << 5);
      float* dst = &Ks[c1 & 1][0];
      #pragma unroll
      for (int u = 0; u < 4; ++u) {
        int n = (w << 8) + (u << 6) + l;
        int kr = n >> 3, s2 = n & 7, m = s2 ^ (kr & 7);
        gload16(src + kr * 128 + (m << 2), dst + (n << 2));
      }
      asm volatile("s_waitcnt vmcnt(4)" ::: "memory");
    } else {
      asm volatile("s_waitcnt vmcnt(0)" ::: "memory");
    }
    asm volatile("s_barrier" ::: "memory");

    {
      const char* qrow0 = qb + (((c & 3) << 3) << 4);   // + (c&3)*128 bytes
      const char* kb2 = (const char*)(&Ks[c & 1][0]) + (kl << 7);
      #pragma unroll
      for (int jj = 0; jj < 8; ++jj) {
        float4 qv[4];
        qv[0] = *(const float4*)(qrow0 + 0 * 512 + ((jj ^ s01) << 4));
        qv[1] = *(const float4*)(qrow0 + 1 * 512 + ((jj ^ s01) << 4));
        qv[2] = *(const float4*)(qrow0 + 2 * 512 + ((jj ^ s23) << 4));
        qv[3] = *(const float4*)(qrow0 + 3 * 512 + ((jj ^ s23) << 4));
        const char* kp = kb2 + (xk16 ^ (jj << 4));
        #pragma unroll
        for (int j2 = 0; j2 < 8; ++j2) {
          float4 kv = *(const float4*)(kp + (j2 << 11));   // +16 rows = 2048B
          #pragma unroll
          for (int i = 0; i < 4; ++i) {
            acc[i][j2] = fmaf(qv[i].x, kv.x, acc[i][j2]);
            acc[i][j2] = fmaf(qv[i].y, kv.y, acc[i][j2]);
            acc[i][j2] = fmaf(qv[i].z, kv.z, acc[i][j2]);
            acc[i][j2] = fmaf(qv[i].w, kv.w, acc[i][j2]);
          }
        }
      }
    }

    if ((c & 3) == 3) {     // end of 128-wide k-tile: masked min1/min2 update
      const int kt0 = (c >> 2) << 7;
      #pragma unroll
      for (int i = 0; i < 4; ++i) {
        const int qrow = qrb + i;
        #pragma unroll
        for (int j2 = 0; j2 < 8; ++j2) {
          const int kg = kt0 + kl + (j2 << 4);
          const bool cand = (kg >= qrow);      // maskf==1 guaranteed here
          const float x = acc[i][j2];
          if (cand && x < rv1[i]) {
            rv2[i] = rv1[i]; ri2[i] = ri1[i];
            rv1[i] = x; ri1[i] = kg;
          } else if (cand && x < rv2[i]) {
            rv2[i] = x; ri2[i] = kg;
          }
          acc[i][j2] = 0.f;
        }
      }
    }
    if (c < 63) asm volatile("s_barrier" ::: "memory");
  }

  asm volatile("s_waitcnt vmcnt(0)" ::: "memory");   // Q loads done (mask=0 path)
  __syncthreads();   // uniform; frees Ks for pass-B scratch

  // ---- butterfly-merge (min1,min2) across the 16 kl lanes ----
  #pragma unroll
  for (int i = 0; i < 4; ++i) {
    #pragma unroll
    for (int st = 1; st <= 8; st <<= 1) {
      float ov1 = __shfl_xor(rv1[i], st);
      int   oi1 = __shfl_xor(ri1[i], st);
      float ov2 = __shfl_xor(rv2[i], st);
      int   oi2 = __shfl_xor(ri2[i], st);
      if (ov1 < rv1[i]) {
        if (rv1[i] < ov2) { rv2[i] = rv1[i]; ri2[i] = ri1[i]; }
        else              { rv2[i] = ov2;    ri2[i] = oi2;    }
        rv1[i] = ov1; ri1[i] = oi1;
      } else if (ov1 < rv2[i]) {
        rv2[i] = ov1; ri2[i] = oi1;
      }
    }
  }

  bool flag[4];
  #pragma unroll
  for (int i = 0; i < 4; ++i) flag[i] = !(rv1[i] < -1e-3f);   // FLT_MAX / mask=0 incl.

  // ---- pass-A epilogue: 2-term one-hot gather for unflagged rows ----
  #pragma unroll
  for (int i = 0; i < 4; ++i) {
    if (!flag[i]) {
      float w2 = __expf((rv1[i] - rv2[i]) * 1.0e9f * INV_DENOM);   // = exp(x2-x1) <= 1
      float nrm = 1.0f / (1.0f + w2);
      const float4* V1 = (const float4*)(Vb + (size_t)ri1[i] * Dc) + (kl << 1);
      const float4* V2 = (const float4*)(Vb + (size_t)ri2[i] * Dc) + (kl << 1);
      float4 a0 = V1[0], a1 = V1[1], b0 = V2[0], b1 = V2[1];
      float4 o0, o1;
      o0.x = (a0.x + w2 * b0.x) * nrm; o0.y = (a0.y + w2 * b0.y) * nrm;
      o0.z = (a0.z + w2 * b0.z) * nrm; o0.w = (a0.w + w2 * b0.w) * nrm;
      o1.x = (a1.x + w2 * b1.x) * nrm; o1.y = (a1.y + w2 * b1.y) * nrm;
      o1.z = (a1.z + w2 * b1.z) * nrm; o1.w = (a1.w + w2 * b1.w) * nrm;
      float4* Or = (float4*)(Og + ((size_t)b * Lc + qrb + i) * Dc) + (kl << 1);
      Or[0] = o0;
      Or[1] = o1;
    }
  }

  // ---- collect per-wave 16-bit flagged-row mask (wave-uniform) ----
  unsigned rowmask = 0;
  #pragma unroll
  for (int i = 0; i < 4; ++i) {
    unsigned long long bal = __ballot((int)flag[i]);
    #pragma unroll
    for (int g = 0; g < 4; ++g)
      rowmask |= ((unsigned)(bal >> (g * 16)) & 1u) << ((g << 2) + i);
  }

  // ---- pass B: exact dense softmax for flagged rows (barrier-free) ----
  if (rowmask) {
    float* scr = &Ks[0][0] + (w << 11);    // 2048 floats per wave
    unsigned rm = rowmask;
    while (rm) {
      const int r = __ffs(rm) - 1; rm &= rm - 1;
      const int qglob = q0 + (w << 4) + r;
      const int rloc = (w << 4) + r;
      const char* qrowB = (const char*)Qs + ((size_t)rloc << 9);
      const int sr = (rloc >> 1) & 7;

      // scores for k = l + 64*tt, masked, write to scratch, track max
      float mx = -FLT_MAX;
      #pragma unroll 2
      for (int tt = 0; tt < 32; ++tt) {
        const int k = (tt << 6) + l;
        const float4* Kr = (const float4*)(Kb + ((size_t)k << 7));
        float s = 0.f;
        #pragma unroll
        for (int j2 = 0; j2 < 32; ++j2) {
          float4 qv = *(const float4*)(qrowB + ((j2 ^ sr) << 4));
          float4 kv = Kr[j2];
          s = fmaf(qv.x, kv.x, s); s = fmaf(qv.y, kv.y, s);
          s = fmaf(qv.z, kv.z, s); s = fmaf(qv.w, kv.w, s);
        }
        const bool msk = maskf && (k >= qglob);
        const float xv = s * (msk ? MNEG : INV_DENOM);
        scr[k] = xv;
        mx = fmaxf(mx, xv);
      }
      #pragma unroll
      for (int st = 1; st <= 32; st <<= 1) mx = fmaxf(mx, __shfl_xor(mx, st));
      asm volatile("s_waitcnt lgkmcnt(0)" ::: "memory");

      float sum = 0.f;
      #pragma unroll 4
      for (int tt = 0; tt < 32; ++tt) {
        const int k = (tt << 6) + l;
        const float p = __expf(scr[k] - mx);
        scr[k] = p;
        sum += p;
      }
      #pragma unroll
      for (int st = 1; st <= 32; st <<= 1) sum += __shfl_xor(sum, st);
      asm volatile("s_waitcnt lgkmcnt(0)" ::: "memory");
      const float inv = 1.0f / sum;

      float2 acc2 = make_float2(0.f, 0.f);
      const float* Vd = Vb + (l << 1);
      #pragma unroll 8
      for (int k = 0; k < 2048; ++k) {
        const float p = scr[k];
        const float2 vv = *(const float2*)(Vd + ((size_t)k << 7));
        acc2.x = fmaf(p, vv.x, acc2.x);
        acc2.y = fmaf(p, vv.y, acc2.y);
      }
      *(float2*)(Og + ((size_t)b * Lc + qglob) * Dc + (l << 1)) =
          make_float2(acc2.x * inv, acc2.y * inv);
    }
  }
}

extern "C" void kernel_launch(void* const* d_in, const int* in_sizes, int n_in,
                              void* d_out, int out_size, void* d_ws, size_t ws_size,
                              hipStream_t stream) {
  (void)in_sizes; (void)n_in; (void)d_ws; (void)ws_size; (void)out_size;
  const float* Q = (const float*)d_in[0];
  const float* K = (const float*)d_in[1];
  const float* V = (const float*)d_in[2];
  const int* M = (const int*)d_in[3];
  float* O = (float*)d_out;
  dim3 grid(Bc * (Lc / 64)), block(256);
  hipLaunchKernelGGL(sda_fwd, grid, block, 0, stream, Q, K, V, M, O);
}